// Round 17
// baseline (91.909 us; speedup 1.0000x reference)
//
#include <hip/hip_runtime.h>

#define SS 784
#define NQE 1605632          // 8*784*256 (elements of one bf16 buffer)

typedef float f32x4 __attribute__((ext_vector_type(4)));
typedef short s16x8 __attribute__((ext_vector_type(8)));

__device__ inline ushort f2bf(float f) {
    union { float f; unsigned u; } v; v.f = f;
    return (ushort)((v.u + 0x7fff + ((v.u >> 16) & 1)) >> 16);
}
__device__ inline float bf2f(ushort h) {
    union { unsigned u; float f; } v; v.u = ((unsigned)h) << 16;
    return v.f;
}
__device__ inline unsigned cvt_pk_bf16(float lo, float hi) {
    unsigned r;
    asm("v_cvt_pk_bf16_f32 %0, %1, %2" : "=v"(r) : "v"(lo), "v"(hi));
    return r;
}

// ---------------- merged Q/K/V projection with fused input transpose ----------------
// One launch, 336 blocks (= 8b * 7p * 6o), b = id%8 -> XCD = b.
// oy 0-1: Q -> qt[b][p][o] (scaled); oy 2-3: K -> kt[b][p][o]; oy 4-5: V -> vv[b][c][p].
// B-path (r17 fix): stage X f32 UNTRANSPOSED+coalesced into padded Xf[32][132]; build
// B-fragments in-register (8 column b32 reads + 4 cvt_pk) -- eliminates the 2B scatter
// writes whose ~16-way conflicts cost ~8 us in r16 (SQ_LDS_BANK_CONFLICT 5.75M).
__global__ __launch_bounds__(256) void gemm_qkv(const float* __restrict__ X0,
                                                const float* __restrict__ X1,
                                                const float* __restrict__ Wq,
                                                const float* __restrict__ bq,
                                                const float* __restrict__ Wkv,
                                                const float* __restrict__ bkv,
                                                ushort* __restrict__ qt,
                                                ushort* __restrict__ kt,
                                                ushort* __restrict__ vv,
                                                float qscale) {
    __shared__ ushort As[128 * 40];   // W rows (o), bf16
    __shared__ float  Xf[32 * 132];   // X tile [c][p], f32, pad 132 (4 mod 32)
    const int id  = blockIdx.x;
    const int b   = id & 7;
    const int sub = id >> 3;
    const int oy  = sub % 6;
    const int p0  = (sub / 6) * 128;
    const int mode = (oy < 2) ? 0 : (oy < 4 ? 1 : 2);
    const float* X    = (mode == 0) ? X0 : X1;
    const float* Wg   = (mode == 0) ? Wq : Wkv;
    const float* bias = (mode == 0) ? bq : bkv;
    const int o0w = (mode == 0) ? oy * 128 : (oy - 2) * 128;

    const int tid = threadIdx.x;
    const int lane = tid & 63, wave = tid >> 6;
    const int wm = wave >> 1, wn = wave & 1;
    const int lg = lane >> 4, lm = lane & 15;
    const int srow = tid >> 1, shalf = (tid & 1) * 16;
    const int bc = tid >> 3;            // 0..31 c-local (B staging)
    const int bp = (tid & 7) * 16;      // p offset  (B staging)

    const f32x4 Z4 = {0.f, 0.f, 0.f, 0.f};
    f32x4 acc[4][4];
    #pragma unroll
    for (int m = 0; m < 4; ++m)
        #pragma unroll
        for (int n = 0; n < 4; ++n) acc[m][n] = Z4;

    const float* Xb = X + (size_t)b * 512 * SS;

    for (int c0 = 0; c0 < 512; c0 += 32) {
        __syncthreads();
        {   // A: W f32 -> bf16
            const float* src = Wg + (size_t)(o0w + srow) * 512 + c0 + shalf;
            ushort tmp[16];
            #pragma unroll
            for (int jj = 0; jj < 4; ++jj) {
                float4 v = *(const float4*)(src + jj * 4);
                tmp[jj * 4 + 0] = f2bf(v.x); tmp[jj * 4 + 1] = f2bf(v.y);
                tmp[jj * 4 + 2] = f2bf(v.z); tmp[jj * 4 + 3] = f2bf(v.w);
            }
            *(s16x8*)&As[srow * 40 + shalf]     = *(s16x8*)&tmp[0];
            *(s16x8*)&As[srow * 40 + shalf + 8] = *(s16x8*)&tmp[8];
        }
        {   // B: X f32 [c][p] coalesced copy (no transpose), zero-fill past SS
            const float* src = Xb + (size_t)(c0 + bc) * SS + p0 + bp;
            float* dst = &Xf[bc * 132 + bp];
            #pragma unroll
            for (int k = 0; k < 4; ++k) {
                f32x4 v = (p0 + bp + 4 * k < SS) ? *(const f32x4*)(src + 4 * k) : Z4;
                *(f32x4*)(dst + 4 * k) = v;
            }
        }
        __syncthreads();
        s16x8 af[4];
        #pragma unroll
        for (int m = 0; m < 4; ++m) af[m] = *(const s16x8*)&As[(wm * 64 + m * 16 + lm) * 40 + 8 * lg];
        #pragma unroll
        for (int n = 0; n < 4; ++n) {
            // B-fragment in-register: B[k=8lg+j][col=p] from Xf columns
            const float* col = &Xf[(8 * lg) * 132 + wn * 64 + n * 16 + lm];
            uint4 pk;
            pk.x = cvt_pk_bf16(col[0 * 132], col[1 * 132]);
            pk.y = cvt_pk_bf16(col[2 * 132], col[3 * 132]);
            pk.z = cvt_pk_bf16(col[4 * 132], col[5 * 132]);
            pk.w = cvt_pk_bf16(col[6 * 132], col[7 * 132]);
            s16x8 bf8 = *(s16x8*)&pk;
            #pragma unroll
            for (int m = 0; m < 4; ++m)
                acc[m][n] = __builtin_amdgcn_mfma_f32_16x16x32_bf16(af[m], bf8, acc[m][n], 0, 0, 0);
        }
    }

    if (mode < 2) {
        ushort* outT = (mode == 0) ? qt : kt;
        const float scale = (mode == 0) ? qscale : 1.0f;
        #pragma unroll
        for (int m = 0; m < 4; ++m) {
            const int o = o0w + wm * 64 + m * 16 + 4 * lg;
            float bv[4];
            #pragma unroll
            for (int r = 0; r < 4; ++r) bv[r] = bias[o + r];
            #pragma unroll
            for (int n = 0; n < 4; ++n) {
                const int p = p0 + wn * 64 + n * 16 + lm;
                if (p < SS) {
                    ushort4 w;
                    w.x = f2bf((acc[m][n][0] + bv[0]) * scale);
                    w.y = f2bf((acc[m][n][1] + bv[1]) * scale);
                    w.z = f2bf((acc[m][n][2] + bv[2]) * scale);
                    w.w = f2bf((acc[m][n][3] + bv[3]) * scale);
                    *(ushort4*)&outT[((size_t)b * SS + p) * 256 + o] = w;
                }
            }
        }
    } else {
        #pragma unroll
        for (int m = 0; m < 4; ++m) {
            const int ob = o0w + wm * 64 + m * 16 + 4 * lg;
            float bv[4];
            #pragma unroll
            for (int r = 0; r < 4; ++r) bv[r] = bias[ob + r];
            #pragma unroll
            for (int n = 0; n < 4; ++n) {
                const int p = p0 + wn * 64 + n * 16 + lm;
                if (p < SS) {
                    #pragma unroll
                    for (int r = 0; r < 4; ++r) {
                        const int c = ob - 256 + r;
                        vv[((size_t)b * 256 + c) * SS + p] = f2bf(acc[m][n][r] + bv[r]);
                    }
                }
            }
        }
    }
}

// ---------------- fused MFMA attention: r12 proven config (sync staging, 16B-aligned rows) -----
// 256 threads, 4 waves, 3 blocks/CU. KROW=280 (560B rows), VROW=PROW=40 (80B rows): all
// b128 LDS ops 16B-aligned. (Tested & rejected: async dbuf r8-r10, stride-"conflict-free"
// r11 (breaks alignment), 8-wave blocks r13-r15 (barrier cost > amortization).)
#define KROW 280
#define VROW 40
#define PROW 40

__global__ __launch_bounds__(256, 3) void attn_mfma(const ushort* __restrict__ qt,
                                                    const ushort* __restrict__ kt,
                                                    const ushort* __restrict__ vv,
                                                    ushort* __restrict__ pb,
                                                    ushort* __restrict__ p4) {
    __shared__ ushort ks[32 * KROW];          // 17920 B
    __shared__ ushort vs[256 * VROW];         // 20480 B
    __shared__ ushort pls[4 * 2 * 16 * PROW]; // 10240 B (per-wave ping-pong P)
    const int tid  = threadIdx.x;
    const int lane = tid & 63;
    const int wave = tid >> 6;
    const int b     = blockIdx.x;             // grid (8,65): linear%8 = b -> XCD = b
    const int stile = blockIdx.y / 5;
    const int ts    = blockIdx.y % 5;
    int strip = stile * 4 + wave;
    const bool valid = (strip < 49);
    if (!valid) strip = 48;
    const int s0 = strip * 16;

    const int lg = lane >> 4, lm = lane & 15;
    const s16x8 Z8 = {0, 0, 0, 0, 0, 0, 0, 0};
    const f32x4 Z4 = {0.f, 0.f, 0.f, 0.f};

    s16x8 qf[8];
    const ushort* qbase = qt + ((size_t)b * SS + s0 + lm) * 256 + 8 * lg;
    #pragma unroll
    for (int n = 0; n < 8; ++n) qf[n] = *(const s16x8*)(qbase + n * 32);

    f32x4 oacc[8][2];
    #pragma unroll
    for (int n = 0; n < 8; ++n) { oacc[n][0] = Z4; oacc[n][1] = Z4; }

    const ushort* ktb = kt + (size_t)b * SS * 256;
    const ushort* vb  = vv + (size_t)b * 256 * SS;
    ushort* pbase = pls + wave * (2 * 16 * PROW);

    for (int ti = ts * 5; ti < ts * 5 + 5; ++ti) {
        const int t0 = ti * 32;
        __syncthreads();
        {   // K tile [32 t][256 c]
            const int row = tid >> 3, ce = (tid & 7) * 32;
            const int t = t0 + row;
            const ushort* src = ktb + (size_t)t * 256 + ce;
            #pragma unroll
            for (int j = 0; j < 4; ++j) {
                s16x8 v = (t < SS) ? *(const s16x8*)(src + 8 * j) : Z8;
                *(s16x8*)&ks[row * KROW + ce + 8 * j] = v;
            }
        }
        {   // V tile [256 c][32 t]
            const ushort* src = vb + (size_t)tid * SS + t0;
            #pragma unroll
            for (int j = 0; j < 4; ++j) {
                s16x8 v = (t0 + 8 * j < SS) ? *(const s16x8*)(src + 8 * j) : Z8;
                *(s16x8*)&vs[tid * VROW + 8 * j] = v;
            }
        }
        __syncthreads();

        // S^T = mfma(K, Q) + head softmax (max-free exp2; q pre-scaled by log2e/sqrt(dk))
        unsigned pku[2][8][2];
        #pragma unroll
        for (int h = 0; h < 2; ++h) {
            f32x4 lacc[8];
            #pragma unroll
            for (int n = 0; n < 8; ++n) {
                s16x8 ak = *(const s16x8*)&ks[(h * 16 + lm) * KROW + n * 32 + 8 * lg];
                lacc[n] = __builtin_amdgcn_mfma_f32_16x16x32_bf16(ak, qf[n], Z4, 0, 0, 0);
            }
            #pragma unroll
            for (int r = 0; r < 4; ++r) {
                float e[8]; float sum = 0.f;
                #pragma unroll
                for (int n = 0; n < 8; ++n) { e[n] = exp2f(lacc[n][r]); sum += e[n]; }
                float inv;
                asm("v_rcp_f32 %0, %1" : "=v"(inv) : "v"(sum));
                #pragma unroll
                for (int n = 0; n < 8; ++n) lacc[n][r] = e[n] * inv;
            }
            #pragma unroll
            for (int n = 0; n < 8; ++n) {
                pku[h][n][0] = cvt_pk_bf16(lacc[n][0], lacc[n][1]);
                pku[h][n][1] = cvt_pk_bf16(lacc[n][2], lacc[n][3]);
            }
        }

        // PV via tiny wave-private ping-pong LDS bounce (in-order per-wave LDS -> no barrier)
        #pragma unroll
        for (int n = 0; n < 8; ++n) {
            ushort* pw = pbase + (n & 1) * (16 * PROW);
            uint2 w0; w0.x = pku[0][n][0]; w0.y = pku[0][n][1];
            *(uint2*)&pw[lm * PROW + 4 * lg] = w0;
            uint2 w1; w1.x = pku[1][n][0]; w1.y = pku[1][n][1];
            *(uint2*)&pw[lm * PROW + 16 + 4 * lg] = w1;
            s16x8 pbf = *(const s16x8*)&pw[lm * PROW + 8 * lg];
            #pragma unroll
            for (int dh = 0; dh < 2; ++dh) {
                s16x8 va = *(const s16x8*)&vs[(n * 32 + dh * 16 + lm) * VROW + 8 * lg];
                oacc[n][dh] = __builtin_amdgcn_mfma_f32_16x16x32_bf16(va, pbf, oacc[n][dh], 0, 0, 0);
            }
        }
    }

    if (valid) {
        ushort* part = (ts < 4) ? (pb + (size_t)ts * NQE) : p4;
        // O^T: s = lm, d = dh*16 + 4lg + r -> f = lm*32 + dh*16 + 4lg + r (r contiguous)
        const size_t base = (size_t)b * 200704 + (size_t)s0 * 32 + lm * 32 + 4 * lg;
        #pragma unroll
        for (int n = 0; n < 8; ++n) {
            #pragma unroll
            for (int dh = 0; dh < 2; ++dh) {
                uint2 w;
                w.x = cvt_pk_bf16(oacc[n][dh][0], oacc[n][dh][1]);
                w.y = cvt_pk_bf16(oacc[n][dh][2], oacc[n][dh][3]);
                *(uint2*)&part[base + n * 25088 + dh * 16] = w;
            }
        }
    }
}

// ---------------- fused sum5 + output projection: out[b][o][p] f32 ; grid (8b, 7p, 4o) -------
__global__ __launch_bounds__(256) void gemm_out5(const ushort* __restrict__ a0,
                                                 const ushort* __restrict__ a1,
                                                 const ushort* __restrict__ a2,
                                                 const ushort* __restrict__ a3,
                                                 const ushort* __restrict__ a4,
                                                 const float* __restrict__ Wg,
                                                 const float* __restrict__ bias,
                                                 float* __restrict__ outp) {
    __shared__ ushort As[128 * 40];   // attn rows (p) x c
    __shared__ ushort Bs[128 * 40];   // Wo rows (o) x c
    const int tid = threadIdx.x;
    const int lane = tid & 63, wave = tid >> 6;
    const int wm = wave >> 1, wn = wave & 1;
    const int lg = lane >> 4, lm = lane & 15;
    const int b  = blockIdx.x;
    const int p0 = blockIdx.y * 128;
    const int o0 = blockIdx.z * 128;
    const int srow = tid >> 1, shalf = (tid & 1) * 16;
    const int tc = tid >> 3;            // 0..31 c-local (A staging)
    const int tp = (tid & 7) * 16;      // p offset (A staging)

    const f32x4 Z4 = {0.f, 0.f, 0.f, 0.f};
    f32x4 acc[4][4];
    #pragma unroll
    for (int m = 0; m < 4; ++m)
        #pragma unroll
        for (int n = 0; n < 4; ++n) acc[m][n] = Z4;

    for (int c0 = 0; c0 < 256; c0 += 32) {
        __syncthreads();
        {   // A: sum 5 partials [c2][p] -> transposed LDS As[p][c]
            const int p = p0 + tp;
            if (p < SS) {
                const size_t off = ((size_t)b * 256 + c0 + tc) * SS + p;
                #pragma unroll
                for (int jj = 0; jj < 2; ++jj) {
                    s16x8 v0 = *(const s16x8*)(a0 + off + 8 * jj);
                    s16x8 v1 = *(const s16x8*)(a1 + off + 8 * jj);
                    s16x8 v2 = *(const s16x8*)(a2 + off + 8 * jj);
                    s16x8 v3 = *(const s16x8*)(a3 + off + 8 * jj);
                    s16x8 v4 = *(const s16x8*)(a4 + off + 8 * jj);
                    #pragma unroll
                    for (int j = 0; j < 8; ++j) {
                        float s = bf2f((ushort)v0[j]) + bf2f((ushort)v1[j]) + bf2f((ushort)v2[j])
                                + bf2f((ushort)v3[j]) + bf2f((ushort)v4[j]);
                        As[(tp + jj * 8 + j) * 40 + tc] = f2bf(s);
                    }
                }
            } else {
                #pragma unroll
                for (int j = 0; j < 16; ++j) As[(tp + j) * 40 + tc] = 0;
            }
        }
        {   // B: Wo f32 -> bf16
            const float* src = Wg + (size_t)(o0 + srow) * 256 + c0 + shalf;
            ushort tmp[16];
            #pragma unroll
            for (int jj = 0; jj < 4; ++jj) {
                float4 v = *(const float4*)(src + jj * 4);
                tmp[jj * 4 + 0] = f2bf(v.x); tmp[jj * 4 + 1] = f2bf(v.y);
                tmp[jj * 4 + 2] = f2bf(v.z); tmp[jj * 4 + 3] = f2bf(v.w);
            }
            *(s16x8*)&Bs[srow * 40 + shalf]     = *(s16x8*)&tmp[0];
            *(s16x8*)&Bs[srow * 40 + shalf + 8] = *(s16x8*)&tmp[8];
        }
        __syncthreads();
        s16x8 af[4], bf[4];
        #pragma unroll
        for (int m = 0; m < 4; ++m) af[m] = *(const s16x8*)&As[(wm * 64 + m * 16 + lm) * 40 + 8 * lg];
        #pragma unroll
        for (int n = 0; n < 4; ++n) bf[n] = *(const s16x8*)&Bs[(wn * 64 + n * 16 + lm) * 40 + 8 * lg];
        #pragma unroll
        for (int m = 0; m < 4; ++m)
            #pragma unroll
            for (int n = 0; n < 4; ++n)
                acc[m][n] = __builtin_amdgcn_mfma_f32_16x16x32_bf16(af[m], bf[n], acc[m][n], 0, 0, 0);
    }

    #pragma unroll
    for (int n = 0; n < 4; ++n) {
        const int o = o0 + wn * 64 + n * 16 + lm;
        const float bv = bias[o];
        #pragma unroll
        for (int m = 0; m < 4; ++m) {
            const int p = p0 + wm * 64 + m * 16 + 4 * lg;
            if (p < SS) {
                f32x4 v;
                #pragma unroll
                for (int r = 0; r < 4; ++r) v[r] = acc[m][n][r] + bv;
                *(f32x4*)&outp[((size_t)b * 512 + o) * SS + p] = v;
            }
        }
    }
}

extern "C" void kernel_launch(void* const* d_in, const int* in_sizes, int n_in,
                              void* d_out, int out_size, void* d_ws, size_t ws_size,
                              hipStream_t stream) {
    const float* inputs    = (const float*)d_in[0];
    const float* inputs_st = (const float*)d_in[1];
    const float* Wq        = (const float*)d_in[2];
    const float* bq        = (const float*)d_in[3];
    const float* Wkv       = (const float*)d_in[4];
    const float* bkv       = (const float*)d_in[5];
    const float* Wo        = (const float*)d_in[6];
    const float* bo        = (const float*)d_in[7];
    float* out = (float*)d_out;

    ushort* W     = (ushort*)d_ws;
    // slots 0-3: partials 0-3 ; slot 4: qt ; slot 5: kt ; slot 6: vv ; slot 7: p4
    ushort* qt    = W + 4 * (size_t)NQE;
    ushort* kt    = W + 5 * (size_t)NQE;
    ushort* vv    = W + 6 * (size_t)NQE;
    ushort* p4    = W + 7 * (size_t)NQE;

    const float qscale = (float)(1.4426950408889634 / 5.656854249492380195); // log2(e)/sqrt(32)

    gemm_qkv<<<dim3(336), dim3(256), 0, stream>>>(inputs, inputs_st, Wq, bq, Wkv, bkv, qt, kt, vv, qscale);
    attn_mfma<<<dim3(8, 65), dim3(256), 0, stream>>>(qt, kt, vv, W, p4);
    gemm_out5<<<dim3(8, 7, 4), dim3(256), 0, stream>>>(W, W + (size_t)NQE, W + 2 * (size_t)NQE,
                                                       W + 3 * (size_t)NQE, p4, Wo, bo, out);
}

// Round 18
// 84.894 us; speedup vs baseline: 1.0826x; 1.0826x over previous
//
#include <hip/hip_runtime.h>

#define SS 784
#define NQE 1605632          // 8*784*256 (elements of one bf16 buffer)

typedef float f32x4 __attribute__((ext_vector_type(4)));
typedef short s16x8 __attribute__((ext_vector_type(8)));

__device__ inline ushort f2bf(float f) {
    union { float f; unsigned u; } v; v.f = f;
    return (ushort)((v.u + 0x7fff + ((v.u >> 16) & 1)) >> 16);
}
__device__ inline float bf2f(ushort h) {
    union { unsigned u; float f; } v; v.u = ((unsigned)h) << 16;
    return v.f;
}
__device__ inline unsigned cvt_pk_bf16(float lo, float hi) {
    unsigned r;
    asm("v_cvt_pk_bf16_f32 %0, %1, %2" : "=v"(r) : "v"(lo), "v"(hi));
    return r;
}

// ---------------- merged Q/K/V projection, p-tile 64 (624 blocks for occupancy) ----------------
// 624 = 8b * (6oy * 13py); id%8 = b -> XCD = b. oy 0-1: Q -> qt[b][p][o] (scaled);
// oy 2-3: K -> kt[b][p][o]; oy 4-5: V -> vv[b][c][p]. Per wave: 64o x 32p (acc[4][2]).
// B: X f32 staged untransposed/coalesced in Xf[32][68]; B-fragments built in-register.
__global__ __launch_bounds__(256) void gemm_qkv(const float* __restrict__ X0,
                                                const float* __restrict__ X1,
                                                const float* __restrict__ Wq,
                                                const float* __restrict__ bq,
                                                const float* __restrict__ Wkv,
                                                const float* __restrict__ bkv,
                                                ushort* __restrict__ qt,
                                                ushort* __restrict__ kt,
                                                ushort* __restrict__ vv,
                                                float qscale) {
    __shared__ ushort As[128 * 40];   // W rows (o), bf16
    __shared__ float  Xf[32 * 68];    // X tile [c][p], f32, pad 68 (4 mod 32)
    const int id  = blockIdx.x;
    const int b   = id & 7;
    const int sub = id >> 3;          // 0..77
    const int oy  = sub % 6;
    const int p0  = (sub / 6) * 64;
    const int mode = (oy < 2) ? 0 : (oy < 4 ? 1 : 2);
    const float* X    = (mode == 0) ? X0 : X1;
    const float* Wg   = (mode == 0) ? Wq : Wkv;
    const float* bias = (mode == 0) ? bq : bkv;
    const int o0w = (mode == 0) ? oy * 128 : (oy - 2) * 128;

    const int tid = threadIdx.x;
    const int lane = tid & 63, wave = tid >> 6;
    const int wm = wave >> 1, wn = wave & 1;
    const int lg = lane >> 4, lm = lane & 15;
    const int srow = tid >> 1, shalf = (tid & 1) * 16;
    const int bc = tid >> 3;            // 0..31 c-local (B staging)
    const int bp = (tid & 7) * 8;       // p offset  (B staging), 8 floats/thread

    const f32x4 Z4 = {0.f, 0.f, 0.f, 0.f};
    f32x4 acc[4][2];
    #pragma unroll
    for (int m = 0; m < 4; ++m)
        #pragma unroll
        for (int n = 0; n < 2; ++n) acc[m][n] = Z4;

    const float* Xb = X + (size_t)b * 512 * SS;

    for (int c0 = 0; c0 < 512; c0 += 32) {
        __syncthreads();
        {   // A: W f32 -> bf16 (128 o rows x 32 c)
            const float* src = Wg + (size_t)(o0w + srow) * 512 + c0 + shalf;
            ushort tmp[16];
            #pragma unroll
            for (int jj = 0; jj < 4; ++jj) {
                float4 v = *(const float4*)(src + jj * 4);
                tmp[jj * 4 + 0] = f2bf(v.x); tmp[jj * 4 + 1] = f2bf(v.y);
                tmp[jj * 4 + 2] = f2bf(v.z); tmp[jj * 4 + 3] = f2bf(v.w);
            }
            *(s16x8*)&As[srow * 40 + shalf]     = *(s16x8*)&tmp[0];
            *(s16x8*)&As[srow * 40 + shalf + 8] = *(s16x8*)&tmp[8];
        }
        {   // B: X f32 [c][p] coalesced copy (no transpose), zero-fill past SS
            const float* src = Xb + (size_t)(c0 + bc) * SS + p0 + bp;
            float* dst = &Xf[bc * 68 + bp];
            #pragma unroll
            for (int k = 0; k < 2; ++k) {
                f32x4 v = (p0 + bp + 4 * k < SS) ? *(const f32x4*)(src + 4 * k) : Z4;
                *(f32x4*)(dst + 4 * k) = v;
            }
        }
        __syncthreads();
        s16x8 af[4];
        #pragma unroll
        for (int m = 0; m < 4; ++m) af[m] = *(const s16x8*)&As[(wm * 64 + m * 16 + lm) * 40 + 8 * lg];
        #pragma unroll
        for (int n = 0; n < 2; ++n) {
            const float* col = &Xf[(8 * lg) * 68 + wn * 32 + n * 16 + lm];
            uint4 pk;
            pk.x = cvt_pk_bf16(col[0 * 68], col[1 * 68]);
            pk.y = cvt_pk_bf16(col[2 * 68], col[3 * 68]);
            pk.z = cvt_pk_bf16(col[4 * 68], col[5 * 68]);
            pk.w = cvt_pk_bf16(col[6 * 68], col[7 * 68]);
            s16x8 bf8 = *(s16x8*)&pk;
            #pragma unroll
            for (int m = 0; m < 4; ++m)
                acc[m][n] = __builtin_amdgcn_mfma_f32_16x16x32_bf16(af[m], bf8, acc[m][n], 0, 0, 0);
        }
    }

    if (mode < 2) {
        ushort* outT = (mode == 0) ? qt : kt;
        const float scale = (mode == 0) ? qscale : 1.0f;
        #pragma unroll
        for (int m = 0; m < 4; ++m) {
            const int o = o0w + wm * 64 + m * 16 + 4 * lg;
            float bv[4];
            #pragma unroll
            for (int r = 0; r < 4; ++r) bv[r] = bias[o + r];
            #pragma unroll
            for (int n = 0; n < 2; ++n) {
                const int p = p0 + wn * 32 + n * 16 + lm;
                if (p < SS) {
                    ushort4 w;
                    w.x = f2bf((acc[m][n][0] + bv[0]) * scale);
                    w.y = f2bf((acc[m][n][1] + bv[1]) * scale);
                    w.z = f2bf((acc[m][n][2] + bv[2]) * scale);
                    w.w = f2bf((acc[m][n][3] + bv[3]) * scale);
                    *(ushort4*)&outT[((size_t)b * SS + p) * 256 + o] = w;
                }
            }
        }
    } else {
        #pragma unroll
        for (int m = 0; m < 4; ++m) {
            const int ob = o0w + wm * 64 + m * 16 + 4 * lg;
            float bv[4];
            #pragma unroll
            for (int r = 0; r < 4; ++r) bv[r] = bias[ob + r];
            #pragma unroll
            for (int n = 0; n < 2; ++n) {
                const int p = p0 + wn * 32 + n * 16 + lm;
                if (p < SS) {
                    #pragma unroll
                    for (int r = 0; r < 4; ++r) {
                        const int c = ob - 256 + r;
                        vv[((size_t)b * 256 + c) * SS + p] = f2bf(acc[m][n][r] + bv[r]);
                    }
                }
            }
        }
    }
}

// ---------------- fused MFMA attention: r12 proven config (sync staging, 16B-aligned rows) -----
// 256 threads, 4 waves, 3 blocks/CU. KROW=280 (560B rows), VROW=PROW=40 (80B rows): all
// b128 LDS ops 16B-aligned. (Tested & rejected: async dbuf r8-r10, stride-"conflict-free"
// r11 (breaks alignment), 8-wave blocks r13-r15 (barrier cost > amortization).)
#define KROW 280
#define VROW 40
#define PROW 40

__global__ __launch_bounds__(256, 3) void attn_mfma(const ushort* __restrict__ qt,
                                                    const ushort* __restrict__ kt,
                                                    const ushort* __restrict__ vv,
                                                    ushort* __restrict__ pb,
                                                    ushort* __restrict__ p4) {
    __shared__ ushort ks[32 * KROW];          // 17920 B
    __shared__ ushort vs[256 * VROW];         // 20480 B
    __shared__ ushort pls[4 * 2 * 16 * PROW]; // 10240 B (per-wave ping-pong P)
    const int tid  = threadIdx.x;
    const int lane = tid & 63;
    const int wave = tid >> 6;
    const int b     = blockIdx.x;             // grid (8,65): linear%8 = b -> XCD = b
    const int stile = blockIdx.y / 5;
    const int ts    = blockIdx.y % 5;
    int strip = stile * 4 + wave;
    const bool valid = (strip < 49);
    if (!valid) strip = 48;
    const int s0 = strip * 16;

    const int lg = lane >> 4, lm = lane & 15;
    const s16x8 Z8 = {0, 0, 0, 0, 0, 0, 0, 0};
    const f32x4 Z4 = {0.f, 0.f, 0.f, 0.f};

    s16x8 qf[8];
    const ushort* qbase = qt + ((size_t)b * SS + s0 + lm) * 256 + 8 * lg;
    #pragma unroll
    for (int n = 0; n < 8; ++n) qf[n] = *(const s16x8*)(qbase + n * 32);

    f32x4 oacc[8][2];
    #pragma unroll
    for (int n = 0; n < 8; ++n) { oacc[n][0] = Z4; oacc[n][1] = Z4; }

    const ushort* ktb = kt + (size_t)b * SS * 256;
    const ushort* vb  = vv + (size_t)b * 256 * SS;
    ushort* pbase = pls + wave * (2 * 16 * PROW);

    for (int ti = ts * 5; ti < ts * 5 + 5; ++ti) {
        const int t0 = ti * 32;
        __syncthreads();
        {   // K tile [32 t][256 c]
            const int row = tid >> 3, ce = (tid & 7) * 32;
            const int t = t0 + row;
            const ushort* src = ktb + (size_t)t * 256 + ce;
            #pragma unroll
            for (int j = 0; j < 4; ++j) {
                s16x8 v = (t < SS) ? *(const s16x8*)(src + 8 * j) : Z8;
                *(s16x8*)&ks[row * KROW + ce + 8 * j] = v;
            }
        }
        {   // V tile [256 c][32 t]
            const ushort* src = vb + (size_t)tid * SS + t0;
            #pragma unroll
            for (int j = 0; j < 4; ++j) {
                s16x8 v = (t0 + 8 * j < SS) ? *(const s16x8*)(src + 8 * j) : Z8;
                *(s16x8*)&vs[tid * VROW + 8 * j] = v;
            }
        }
        __syncthreads();

        // S^T = mfma(K, Q) + head softmax (max-free exp2; q pre-scaled by log2e/sqrt(dk))
        unsigned pku[2][8][2];
        #pragma unroll
        for (int h = 0; h < 2; ++h) {
            f32x4 lacc[8];
            #pragma unroll
            for (int n = 0; n < 8; ++n) {
                s16x8 ak = *(const s16x8*)&ks[(h * 16 + lm) * KROW + n * 32 + 8 * lg];
                lacc[n] = __builtin_amdgcn_mfma_f32_16x16x32_bf16(ak, qf[n], Z4, 0, 0, 0);
            }
            #pragma unroll
            for (int r = 0; r < 4; ++r) {
                float e[8]; float sum = 0.f;
                #pragma unroll
                for (int n = 0; n < 8; ++n) { e[n] = exp2f(lacc[n][r]); sum += e[n]; }
                float inv;
                asm("v_rcp_f32 %0, %1" : "=v"(inv) : "v"(sum));
                #pragma unroll
                for (int n = 0; n < 8; ++n) lacc[n][r] = e[n] * inv;
            }
            #pragma unroll
            for (int n = 0; n < 8; ++n) {
                pku[h][n][0] = cvt_pk_bf16(lacc[n][0], lacc[n][1]);
                pku[h][n][1] = cvt_pk_bf16(lacc[n][2], lacc[n][3]);
            }
        }

        // PV via tiny wave-private ping-pong LDS bounce (in-order per-wave LDS -> no barrier)
        #pragma unroll
        for (int n = 0; n < 8; ++n) {
            ushort* pw = pbase + (n & 1) * (16 * PROW);
            uint2 w0; w0.x = pku[0][n][0]; w0.y = pku[0][n][1];
            *(uint2*)&pw[lm * PROW + 4 * lg] = w0;
            uint2 w1; w1.x = pku[1][n][0]; w1.y = pku[1][n][1];
            *(uint2*)&pw[lm * PROW + 16 + 4 * lg] = w1;
            s16x8 pbf = *(const s16x8*)&pw[lm * PROW + 8 * lg];
            #pragma unroll
            for (int dh = 0; dh < 2; ++dh) {
                s16x8 va = *(const s16x8*)&vs[(n * 32 + dh * 16 + lm) * VROW + 8 * lg];
                oacc[n][dh] = __builtin_amdgcn_mfma_f32_16x16x32_bf16(va, pbf, oacc[n][dh], 0, 0, 0);
            }
        }
    }

    if (valid) {
        ushort* part = (ts < 4) ? (pb + (size_t)ts * NQE) : p4;
        // O^T: s = lm, d = dh*16 + 4lg + r -> f = lm*32 + dh*16 + 4lg + r (r contiguous)
        const size_t base = (size_t)b * 200704 + (size_t)s0 * 32 + lm * 32 + 4 * lg;
        #pragma unroll
        for (int n = 0; n < 8; ++n) {
            #pragma unroll
            for (int dh = 0; dh < 2; ++dh) {
                uint2 w;
                w.x = cvt_pk_bf16(oacc[n][dh][0], oacc[n][dh][1]);
                w.y = cvt_pk_bf16(oacc[n][dh][2], oacc[n][dh][3]);
                *(uint2*)&part[base + n * 25088 + dh * 16] = w;
            }
        }
    }
}

// ---------------- fused sum5 + output projection, p-tile 64: grid (8b, 13p, 4o) -------
// Per wave: 32p x 64o (acc[2][4]). A-staging sums 5 partials [c2][p] -> transposed As[p][c].
__global__ __launch_bounds__(256) void gemm_out5(const ushort* __restrict__ a0,
                                                 const ushort* __restrict__ a1,
                                                 const ushort* __restrict__ a2,
                                                 const ushort* __restrict__ a3,
                                                 const ushort* __restrict__ a4,
                                                 const float* __restrict__ Wg,
                                                 const float* __restrict__ bias,
                                                 float* __restrict__ outp) {
    __shared__ ushort As[64 * 40];    // attn rows (p) x c
    __shared__ ushort Bs[128 * 40];   // Wo rows (o) x c
    const int tid = threadIdx.x;
    const int lane = tid & 63, wave = tid >> 6;
    const int wm = wave >> 1, wn = wave & 1;
    const int lg = lane >> 4, lm = lane & 15;
    const int b  = blockIdx.x;
    const int p0 = blockIdx.y * 64;
    const int o0 = blockIdx.z * 128;
    const int srow = tid >> 1, shalf = (tid & 1) * 16;
    const int tc = tid >> 3;            // 0..31 c-local (A staging)
    const int tp = (tid & 7) * 8;       // p offset (A staging), 8 per thread

    const f32x4 Z4 = {0.f, 0.f, 0.f, 0.f};
    f32x4 acc[2][4];
    #pragma unroll
    for (int m = 0; m < 2; ++m)
        #pragma unroll
        for (int n = 0; n < 4; ++n) acc[m][n] = Z4;

    for (int c0 = 0; c0 < 256; c0 += 32) {
        __syncthreads();
        {   // A: sum 5 partials [c2][p] -> transposed LDS As[p][c]
            const int p = p0 + tp;
            if (p < SS) {
                const size_t off = ((size_t)b * 256 + c0 + tc) * SS + p;
                s16x8 v0 = *(const s16x8*)(a0 + off);
                s16x8 v1 = *(const s16x8*)(a1 + off);
                s16x8 v2 = *(const s16x8*)(a2 + off);
                s16x8 v3 = *(const s16x8*)(a3 + off);
                s16x8 v4 = *(const s16x8*)(a4 + off);
                #pragma unroll
                for (int j = 0; j < 8; ++j) {
                    float s = bf2f((ushort)v0[j]) + bf2f((ushort)v1[j]) + bf2f((ushort)v2[j])
                            + bf2f((ushort)v3[j]) + bf2f((ushort)v4[j]);
                    As[(tp + j) * 40 + tc] = f2bf(s);
                }
            } else {
                #pragma unroll
                for (int j = 0; j < 8; ++j) As[(tp + j) * 40 + tc] = 0;
            }
        }
        {   // B: Wo f32 -> bf16 (128 o rows x 32 c)
            const float* src = Wg + (size_t)(o0 + srow) * 256 + c0 + shalf;
            ushort tmp[16];
            #pragma unroll
            for (int jj = 0; jj < 4; ++jj) {
                float4 v = *(const float4*)(src + jj * 4);
                tmp[jj * 4 + 0] = f2bf(v.x); tmp[jj * 4 + 1] = f2bf(v.y);
                tmp[jj * 4 + 2] = f2bf(v.z); tmp[jj * 4 + 3] = f2bf(v.w);
            }
            *(s16x8*)&Bs[srow * 40 + shalf]     = *(s16x8*)&tmp[0];
            *(s16x8*)&Bs[srow * 40 + shalf + 8] = *(s16x8*)&tmp[8];
        }
        __syncthreads();
        s16x8 af[2], bf[4];
        #pragma unroll
        for (int m = 0; m < 2; ++m) af[m] = *(const s16x8*)&As[(wm * 32 + m * 16 + lm) * 40 + 8 * lg];
        #pragma unroll
        for (int n = 0; n < 4; ++n) bf[n] = *(const s16x8*)&Bs[(wn * 64 + n * 16 + lm) * 40 + 8 * lg];
        #pragma unroll
        for (int m = 0; m < 2; ++m)
            #pragma unroll
            for (int n = 0; n < 4; ++n)
                acc[m][n] = __builtin_amdgcn_mfma_f32_16x16x32_bf16(af[m], bf[n], acc[m][n], 0, 0, 0);
    }

    #pragma unroll
    for (int n = 0; n < 4; ++n) {
        const int o = o0 + wn * 64 + n * 16 + lm;
        const float bv = bias[o];
        #pragma unroll
        for (int m = 0; m < 2; ++m) {
            const int p = p0 + wm * 32 + m * 16 + 4 * lg;
            if (p < SS) {
                f32x4 v;
                #pragma unroll
                for (int r = 0; r < 4; ++r) v[r] = acc[m][n][r] + bv;
                *(f32x4*)&outp[((size_t)b * 512 + o) * SS + p] = v;
            }
        }
    }
}

extern "C" void kernel_launch(void* const* d_in, const int* in_sizes, int n_in,
                              void* d_out, int out_size, void* d_ws, size_t ws_size,
                              hipStream_t stream) {
    const float* inputs    = (const float*)d_in[0];
    const float* inputs_st = (const float*)d_in[1];
    const float* Wq        = (const float*)d_in[2];
    const float* bq        = (const float*)d_in[3];
    const float* Wkv       = (const float*)d_in[4];
    const float* bkv       = (const float*)d_in[5];
    const float* Wo        = (const float*)d_in[6];
    const float* bo        = (const float*)d_in[7];
    float* out = (float*)d_out;

    ushort* W     = (ushort*)d_ws;
    // slots 0-3: partials 0-3 ; slot 4: qt ; slot 5: kt ; slot 6: vv ; slot 7: p4
    ushort* qt    = W + 4 * (size_t)NQE;
    ushort* kt    = W + 5 * (size_t)NQE;
    ushort* vv    = W + 6 * (size_t)NQE;
    ushort* p4    = W + 7 * (size_t)NQE;

    const float qscale = (float)(1.4426950408889634 / 5.656854249492380195); // log2(e)/sqrt(32)

    gemm_qkv<<<dim3(624), dim3(256), 0, stream>>>(inputs, inputs_st, Wq, bq, Wkv, bkv, qt, kt, vv, qscale);
    attn_mfma<<<dim3(8, 65), dim3(256), 0, stream>>>(qt, kt, vv, W, p4);
    gemm_out5<<<dim3(8, 13, 4), dim3(256), 0, stream>>>(W, W + (size_t)NQE, W + 2 * (size_t)NQE,
                                                        W + 3 * (size_t)NQE, p4, Wo, bo, out);
}